// Round 11
// baseline (92.319 us; speedup 1.0000x reference)
//
#include <hip/hip_runtime.h>
#include <math.h>

#define NLAT 360
#define NLON 720
#define LMAX 360
#define MMAX 361
#define KPAD 368    // stage-1 col space per (b,c): 32*368 = 11776 cols
#define KP2  384    // XR k-stride (shorts); [0,368) written, [368,384) never touched
#define FT_COLS 736 // DFT K padded to multiple of 32
#define FT_ROWS_PAD 384
#define NJ   32     // 32 (b,c) pairs
#define XST  744    // stage-1 LDS k-stride (shorts)

typedef __attribute__((ext_vector_type(4))) float f32x4;
typedef __attribute__((ext_vector_type(8))) short bf16x8;

__device__ __forceinline__ short f2bf(float f) {
    union { float f; unsigned u; } v; v.f = f;
    unsigned r = (v.u + 0x7FFFu + ((v.u >> 16) & 1u)) >> 16;
    return (short)r;
}

// ------- kernel 0: bf16 cosine-DFT matrix FT[m][n], pads written as 0 ------
__global__ __launch_bounds__(256) void fill_ft_kernel(short* __restrict__ FT) {
    int idx = blockIdx.x * 256 + threadIdx.x;
    const int total = FT_ROWS_PAD * FT_COLS;
    if (idx >= total) return;
    int n = idx % FT_COLS;
    int m = idx / FT_COLS;
    short val = 0;
    if (m < MMAX && n < NLON) {
        int t = (m * n) % NLON;               // exact integer angle reduction
        float s, c;
        sincospif((float)t / 360.0f, &s, &c); // cos(2pi*t/720)
        val = f2bf((6.283185307179586f / 720.0f) * c);
    }
    FT[idx] = val;
}

// ---------------- stage 1: single-pass x-panel kernel (validated r10) ------
__global__ __launch_bounds__(512) void stage1_kernel(const float* __restrict__ x,
                                                     const short* __restrict__ FT,
                                                     short* __restrict__ XR,
                                                     int m0, int cm) {
    __shared__ __align__(16) short Xs[64][XST];
    const int tid  = threadIdx.x;
    const int wav  = tid >> 6;
    const int lane = tid & 63;
    const int col0 = blockIdx.x * 64;
    const int m_hi = (m0 + cm < MMAX) ? (m0 + cm) : MMAX;

    for (int p = tid; p < 64 * 92; p += 512) {
        const int row = p / 92;
        const int c   = p - row * 92;
        const int gb  = col0 + row;
        const int bc  = gb / KPAD;
        const int kl  = gb - bc * KPAD;
        f32x4 va = {0,0,0,0}, vb = {0,0,0,0};
        if (c < 90 && kl < NLAT) {
            const float* xp = x + ((size_t)bc * NLAT + kl) * NLON + c * 8;
            va = *(const f32x4*)xp;
            vb = *(const f32x4*)(xp + 4);
        }
        bf16x8 wv;
        #pragma unroll
        for (int e = 0; e < 4; ++e) { wv[e] = f2bf(va[e]); wv[e + 4] = f2bf(vb[e]); }
        *(bf16x8*)&Xs[row][c * 8] = wv;
    }
    __syncthreads();

    const int r    = lane & 15;
    const int kg   = (lane >> 4) * 8;
    const int rowg = (lane >> 4) * 4;

    for (int mb = m0; mb < m_hi; mb += 256) {
        const int mwb = mb + wav * 32;
        if (mwb >= m_hi) continue;
        const short* ap0 = FT + (size_t)(mwb + r) * FT_COLS + kg;
        const short* ap1 = FT + (size_t)(mwb + 16 + r) * FT_COLS + kg;

        f32x4 acc0[4] = {{0,0,0,0},{0,0,0,0},{0,0,0,0},{0,0,0,0}};
        f32x4 acc1[4] = {{0,0,0,0},{0,0,0,0},{0,0,0,0},{0,0,0,0}};

        bf16x8 A0c = *(const bf16x8*)ap0;
        bf16x8 A1c = *(const bf16x8*)ap1;
        #pragma unroll
        for (int t = 0; t < 23; ++t) {
            bf16x8 A0n, A1n;
            if (t < 22) {
                A0n = *(const bf16x8*)(ap0 + (t + 1) * 32);
                A1n = *(const bf16x8*)(ap1 + (t + 1) * 32);
            }
            #pragma unroll
            for (int f = 0; f < 4; ++f) {
                bf16x8 bfr = *(const bf16x8*)&Xs[f * 16 + r][t * 32 + kg];
                acc0[f] = __builtin_amdgcn_mfma_f32_16x16x32_bf16(A0c, bfr, acc0[f], 0, 0, 0);
                acc1[f] = __builtin_amdgcn_mfma_f32_16x16x32_bf16(A1c, bfr, acc1[f], 0, 0, 0);
            }
            A0c = A0n; A1c = A1n;
        }

        #pragma unroll
        for (int f = 0; f < 4; ++f) {
            const int gb = col0 + f * 16 + r;
            const int bc = gb / KPAD;
            const int kl = gb - bc * KPAD;
            #pragma unroll
            for (int i = 0; i < 4; ++i) {
                const int ma = mwb + rowg + i;
                const int mc = ma + 16;
                if (ma < m_hi)
                    XR[((size_t)(ma - m0) * NJ + bc) * KP2 + kl] = f2bf(acc0[f][i]);
                if (mc < m_hi)
                    XR[((size_t)(mc - m0) * NJ + bc) * KP2 + kl] = f2bf(acc1[f][i]);
            }
        }
    }
}

// ---------------- stage 2: branch-free K-loop, compacted triangle grid -----
// Block 512 thr = 8 waves = (2 l-halves) x (4 m-pairs); tile 32l x 32bc x 8m.
// All loads unconditional from clamped pointers; triangle rows read genuine
// W zeros -> correct zero outputs. Tail step (k=352..360) handled explicitly.
#define S2_LOADU(kk, Xa0, Xa1, Xb0, Xb1, Ya0, Ya1, Yb0, Yb1)                    \
  {                                                                             \
    Xa0 = *(const f32x4*)(wp0 + (kk));                                          \
    Xa1 = *(const f32x4*)(wp0 + (kk) + 4);                                      \
    Xb0 = *(const f32x4*)(wp1 + (kk));                                          \
    Xb1 = *(const f32x4*)(wp1 + (kk) + 4);                                      \
    Ya0 = *(const bf16x8*)(xq0 + (kk));                                         \
    Ya1 = *(const bf16x8*)(xq0 + 16 * KP2 + (kk));                              \
    Yb0 = *(const bf16x8*)(xq1 + (kk));                                         \
    Yb1 = *(const bf16x8*)(xq1 + 16 * KP2 + (kk));                              \
  }

#define S2_COMP(Xa0, Xa1, Xb0, Xb1, Ya0, Ya1, Yb0, Yb1)                         \
  {                                                                             \
    bf16x8 af0, af1;                                                            \
    _Pragma("unroll")                                                           \
    for (int e = 0; e < 4; ++e) {                                               \
      af0[e] = f2bf(Xa0[e]); af0[e + 4] = f2bf(Xa1[e]);                         \
      af1[e] = f2bf(Xb0[e]); af1[e + 4] = f2bf(Xb1[e]);                         \
    }                                                                           \
    acc00 = __builtin_amdgcn_mfma_f32_16x16x32_bf16(af0, Ya0, acc00, 0, 0, 0);  \
    acc01 = __builtin_amdgcn_mfma_f32_16x16x32_bf16(af0, Ya1, acc01, 0, 0, 0);  \
    acc10 = __builtin_amdgcn_mfma_f32_16x16x32_bf16(af1, Yb0, acc10, 0, 0, 0);  \
    acc11 = __builtin_amdgcn_mfma_f32_16x16x32_bf16(af1, Yb1, acc11, 0, 0, 0);  \
  }

__global__ __launch_bounds__(512) void stage2_kernel(const float* __restrict__ W,
                                                     const short* __restrict__ XR,
                                                     float* __restrict__ out,
                                                     int m0, int m_hi) {
    // compacted grid decode: blocks per m-tile = 12 - ((m0 + mt*8) >> 5)
    int bid = blockIdx.x;
    int mt = 0;
    for (;;) {
        const int c = 12 - ((m0 + mt * 8) >> 5);
        if (bid < c) break;
        bid -= c; ++mt;
    }
    const int ltile = ((m0 + mt * 8) >> 5) + bid;

    const int tid  = threadIdx.x;
    const int wav  = tid >> 6;           // 0..7
    const int lane = tid & 63;
    const int l0   = ltile * 32 + (wav & 1) * 16;
    const int mA0  = m0 + mt * 8 + (wav >> 1) * 2;
    const int mA1  = mA0 + 1;
    const int r    = lane & 15;
    const int kg   = (lane >> 4) * 8;

    const int lC   = (l0 + r < LMAX) ? (l0 + r) : (LMAX - 1);
    const int mc0  = (mA0 < m_hi) ? mA0 : (m_hi - 1);
    const int mc1  = (mA1 < m_hi) ? mA1 : (m_hi - 1);

    const float* wp0 = W + ((size_t)mc0 * LMAX + lC) * NLAT + kg;
    const float* wp1 = W + ((size_t)mc1 * LMAX + lC) * NLAT + kg;
    const short* xb0 = XR + ((size_t)(mc0 - m0) * NJ + r) * KP2;  // no kg
    const short* xb1 = XR + ((size_t)(mc1 - m0) * NJ + r) * KP2;
    const short* xq0 = xb0 + kg;
    const short* xq1 = xb1 + kg;

    f32x4 acc00 = {0,0,0,0}, acc01 = {0,0,0,0}, acc10 = {0,0,0,0}, acc11 = {0,0,0,0};

    f32x4 Aa0, Aa1, Ab0, Ab1;
    bf16x8 Ba0, Ba1, Bb0, Bb1;
    f32x4 Pa0, Pa1, Pb0, Pb1;
    bf16x8 Qa0, Qa1, Qb0, Qb1;

    S2_LOADU(0, Aa0, Aa1, Ab0, Ab1, Ba0, Ba1, Bb0, Bb1);
    #pragma unroll
    for (int t = 0; t < 11; ++t) {
        const int kn = (t + 1) * 32;
        if ((t & 1) == 0) {
            if (t < 10) { S2_LOADU(kn, Pa0, Pa1, Pb0, Pb1, Qa0, Qa1, Qb0, Qb1); }
            else {
                // tail prefetch: k = 352..384; A from row+352 (mask kg!=0 after),
                // B from clamped min(352+kg,360) -> [352,368), zeros beyond 360
                const int tb = (352 + kg < 360) ? (352 + kg) : 360;
                Pa0 = *(const f32x4*)(wp0 - kg + 352);
                Pa1 = *(const f32x4*)(wp0 - kg + 356);
                Pb0 = *(const f32x4*)(wp1 - kg + 352);
                Pb1 = *(const f32x4*)(wp1 - kg + 356);
                if (kg) {
                    f32x4 z4 = {0,0,0,0};
                    Pa0 = z4; Pa1 = z4; Pb0 = z4; Pb1 = z4;
                }
                Qa0 = *(const bf16x8*)(xb0 + tb);
                Qa1 = *(const bf16x8*)(xb0 + 16 * KP2 + tb);
                Qb0 = *(const bf16x8*)(xb1 + tb);
                Qb1 = *(const bf16x8*)(xb1 + 16 * KP2 + tb);
            }
            S2_COMP(Aa0, Aa1, Ab0, Ab1, Ba0, Ba1, Bb0, Bb1);
        } else {
            S2_LOADU(kn, Aa0, Aa1, Ab0, Ab1, Ba0, Ba1, Bb0, Bb1);
            S2_COMP(Pa0, Pa1, Pb0, Pb1, Qa0, Qa1, Qb0, Qb1);
        }
    }
    // t=11 (tail) compute: sits in P/Q (t=10 was even: prefetched tail into P/Q)
    S2_COMP(Pa0, Pa1, Pb0, Pb1, Qa0, Qa1, Qb0, Qb1);

    // epilogue: row = l0+(lane>>4)*4+i (l), col = f*16+r (bc); m-pair stores
    const int rowg = (lane >> 4) * 4;
    #pragma unroll
    for (int f = 0; f < 2; ++f) {
        const int j = f * 16 + r;
        const f32x4 c0 = (f == 0) ? acc00 : acc01;
        const f32x4 c1 = (f == 0) ? acc10 : acc11;
        #pragma unroll
        for (int i = 0; i < 4; ++i) {
            const int l = l0 + rowg + i;
            if (l < LMAX) {
                float* op = out + ((size_t)j * LMAX + l) * MMAX + mA0;
                if (mA0 < m_hi) op[0] = c0[i];
                if (mA1 < m_hi) op[1] = c1[i];
            }
        }
    }
}

extern "C" void kernel_launch(void* const* d_in, const int* in_sizes, int n_in,
                              void* d_out, int out_size, void* d_ws, size_t ws_size,
                              hipStream_t stream) {
    const float* x = (const float*)d_in[0];
    const float* w = (const float*)d_in[1];
    float* out = (float*)d_out;

    const size_t XR_OFF = (size_t)FT_ROWS_PAD * FT_COLS * 2;  // 565,248 B
    const size_t PER_M  = (size_t)NJ * KP2 * 2;               // 24,576 B per mode
    long cm = 0;
    if (d_ws != nullptr && ws_size > XR_OFF + PER_M) cm = (long)((ws_size - XR_OFF) / PER_M);
    if (cm > MMAX) cm = MMAX;
    if (cm < 1) return;  // ws proven >= 10.05 MB in round 5; unreachable

    short* FT = (short*)d_ws;
    short* XR = (short*)((char*)d_ws + XR_OFF);
    fill_ft_kernel<<<(FT_ROWS_PAD * FT_COLS + 255) / 256, 256, 0, stream>>>(FT);
    for (int m0 = 0; m0 < MMAX; m0 += (int)cm) {
        const int cmx = ((int)cm < MMAX - m0) ? (int)cm : (MMAX - m0);
        stage1_kernel<<<dim3(184), 512, 0, stream>>>(x, FT, XR, m0, cmx);
        const int gym = (cmx + 7) / 8;
        int nblk = 0;
        for (int mtt = 0; mtt < gym; ++mtt) nblk += 12 - ((m0 + mtt * 8) >> 5);
        stage2_kernel<<<dim3(nblk), 512, 0, stream>>>(w, XR, out, m0, m0 + cmx);
    }
}

// Round 12
// 80.528 us; speedup vs baseline: 1.1464x; 1.1464x over previous
//
#include <hip/hip_runtime.h>
#include <math.h>

#define NLAT 360
#define NLON 720
#define LMAX 360
#define MMAX 361
#define KPADC 384   // stage-1 cols per bc: 192 kf x 2 (s) ; 32*384 = 12288 cols
#define KFP  192    // folded-k padded length (180 data + 12 zero pad)
#define FT_COLS 736 // DFT K padded to multiple of 32
#define FT_ROWS_PAD 384
#define NJ   32     // 32 (b,c) pairs
#define XST  744    // stage-1 LDS k-stride (shorts)

typedef __attribute__((ext_vector_type(4))) float f32x4;
typedef __attribute__((ext_vector_type(8))) short bf16x8;

__device__ __forceinline__ short f2bf(float f) {
    union { float f; unsigned u; } v; v.f = f;
    unsigned r = (v.u + 0x7FFFu + ((v.u >> 16) & 1u)) >> 16;
    return (short)r;
}

// ------- kernel 0: bf16 cosine-DFT matrix FT[m][n], pads written as 0 ------
__global__ __launch_bounds__(256) void fill_ft_kernel(short* __restrict__ FT) {
    int idx = blockIdx.x * 256 + threadIdx.x;
    const int total = FT_ROWS_PAD * FT_COLS;
    if (idx >= total) return;
    int n = idx % FT_COLS;
    int m = idx / FT_COLS;
    short val = 0;
    if (m < MMAX && n < NLON) {
        int t = (m * n) % NLON;               // exact integer angle reduction
        float s, c;
        sincospif((float)t / 360.0f, &s, &c); // cos(2pi*t/720)
        val = f2bf((6.283185307179586f / 720.0f) * c);
    }
    FT[idx] = val;
}

// ---------------- stage 1: x-panel DFT + parity fold -----------------------
// Col space: col = bc*384 + kf*2 + s, klat = s ? 359-kf : kf (kf<180 valid).
// After GEMM, fold via shfl_xor(1): E = C(s0)+C(s1), O = C(s0)-C(s1).
// Writes EO[mloc][e][bc][KFP] bf16; pads kf in [180,192) become exact zeros.
__global__ __launch_bounds__(512) void stage1_kernel(const float* __restrict__ x,
                                                     const short* __restrict__ FT,
                                                     short* __restrict__ EO,
                                                     int m0, int cm) {
    __shared__ __align__(16) short Xs[64][XST];
    const int tid  = threadIdx.x;
    const int wav  = tid >> 6;
    const int lane = tid & 63;
    const int col0 = blockIdx.x * 64;
    const int m_hi = (m0 + cm < MMAX) ? (m0 + cm) : MMAX;

    // staging: 64 rows x 92 chunks of 8 (720 data + 16 zero pad in n)
    for (int p = tid; p < 64 * 92; p += 512) {
        const int row = p / 92;
        const int c   = p - row * 92;
        const int gb  = col0 + row;
        const int bc  = gb / KPADC;
        const int q   = gb - bc * KPADC;
        const int kf  = q >> 1;
        const int s   = q & 1;
        const int klat = s ? (NLAT - 1 - kf) : kf;
        f32x4 va = {0,0,0,0}, vb = {0,0,0,0};
        if (c < 90 && kf < 180) {
            const float* xp = x + ((size_t)bc * NLAT + klat) * NLON + c * 8;
            va = *(const f32x4*)xp;
            vb = *(const f32x4*)(xp + 4);
        }
        bf16x8 wv;
        #pragma unroll
        for (int e = 0; e < 4; ++e) { wv[e] = f2bf(va[e]); wv[e + 4] = f2bf(vb[e]); }
        *(bf16x8*)&Xs[row][c * 8] = wv;
    }
    __syncthreads();

    const int r    = lane & 15;
    const int kg   = (lane >> 4) * 8;
    const int rowg = (lane >> 4) * 4;

    for (int mb = m0; mb < m_hi; mb += 256) {
        const int mwb = mb + wav * 32;
        if (mwb >= m_hi) continue;
        int mA0 = mwb + r;      if (mA0 > FT_ROWS_PAD - 1) mA0 = FT_ROWS_PAD - 1;
        int mA1 = mwb + 16 + r; if (mA1 > FT_ROWS_PAD - 1) mA1 = FT_ROWS_PAD - 1;
        const short* ap0 = FT + (size_t)mA0 * FT_COLS + kg;
        const short* ap1 = FT + (size_t)mA1 * FT_COLS + kg;

        f32x4 acc0[4] = {{0,0,0,0},{0,0,0,0},{0,0,0,0},{0,0,0,0}};
        f32x4 acc1[4] = {{0,0,0,0},{0,0,0,0},{0,0,0,0},{0,0,0,0}};

        bf16x8 A0c = *(const bf16x8*)ap0;
        bf16x8 A1c = *(const bf16x8*)ap1;
        #pragma unroll
        for (int t = 0; t < 23; ++t) {
            bf16x8 A0n, A1n;
            if (t < 22) {
                A0n = *(const bf16x8*)(ap0 + (t + 1) * 32);
                A1n = *(const bf16x8*)(ap1 + (t + 1) * 32);
            }
            #pragma unroll
            for (int f = 0; f < 4; ++f) {
                bf16x8 bfr = *(const bf16x8*)&Xs[f * 16 + r][t * 32 + kg];
                acc0[f] = __builtin_amdgcn_mfma_f32_16x16x32_bf16(A0c, bfr, acc0[f], 0, 0, 0);
                acc1[f] = __builtin_amdgcn_mfma_f32_16x16x32_bf16(A1c, bfr, acc1[f], 0, 0, 0);
            }
            A0c = A0n; A1c = A1n;
        }

        // epilogue: fold pairs (s=0,1) across adjacent lanes, store E/O
        #pragma unroll
        for (int f = 0; f < 4; ++f) {
            const int col = col0 + f * 16 + r;
            const int bc  = col / KPADC;
            const int q   = col - bc * KPADC;
            const int kf  = q >> 1;
            const int e   = q & 1;      // == r & 1
            #pragma unroll
            for (int i = 0; i < 4; ++i) {
                const int ma = mwb + rowg + i;
                const int mc = ma + 16;
                float v0 = acc0[f][i];
                float p0 = __shfl_xor(v0, 1);
                float val0 = e ? (p0 - v0) : (v0 + p0);
                float v1 = acc1[f][i];
                float p1 = __shfl_xor(v1, 1);
                float val1 = e ? (p1 - v1) : (v1 + p1);
                if (ma < m_hi)
                    EO[(((size_t)(ma - m0) * 2 + e) * NJ + bc) * KFP + kf] = f2bf(val0);
                if (mc < m_hi)
                    EO[(((size_t)(mc - m0) * 2 + e) * NJ + bc) * KFP + kf] = f2bf(val1);
            }
        }
    }
}

// ---------------- stage 2: parity-folded GEMM, 6 uniform K-steps -----------
// Grid (2 bc-halves, nblk compacted (ltile,mt8)); block 512 thr = 8 waves = 8 m.
// Wave: 32l x 16bc x 1m; A split even/odd l-parity rows; B = E / O rows.
// W garbage at kf>=180 is killed by EO's zero pads -> no masking anywhere.
#define S2F_LOAD(kk, XE0, XE1, XO0, XO1, YE, YO)                                \
  {                                                                             \
    XE0 = *(const f32x4*)(wpE + (kk));                                          \
    XE1 = *(const f32x4*)(wpE + (kk) + 4);                                      \
    XO0 = *(const f32x4*)(wpO + (kk));                                          \
    XO1 = *(const f32x4*)(wpO + (kk) + 4);                                      \
    YE  = *(const bf16x8*)(eb + (kk));                                          \
    YO  = *(const bf16x8*)(ob + (kk));                                          \
  }

#define S2F_COMP(XE0, XE1, XO0, XO1, YE, YO)                                    \
  {                                                                             \
    bf16x8 afE, afO;                                                            \
    _Pragma("unroll")                                                           \
    for (int e = 0; e < 4; ++e) {                                               \
      afE[e] = f2bf(XE0[e]); afE[e + 4] = f2bf(XE1[e]);                         \
      afO[e] = f2bf(XO0[e]); afO[e + 4] = f2bf(XO1[e]);                         \
    }                                                                           \
    accE = __builtin_amdgcn_mfma_f32_16x16x32_bf16(afE, YE, accE, 0, 0, 0);     \
    accO = __builtin_amdgcn_mfma_f32_16x16x32_bf16(afO, YO, accO, 0, 0, 0);     \
  }

__global__ __launch_bounds__(512) void stage2_kernel(const float* __restrict__ W,
                                                     const short* __restrict__ EO,
                                                     float* __restrict__ out,
                                                     int m0, int m_hi) {
    // compacted grid decode: blocks per 8-m tile = 12 - ((m0 + mt*8) >> 5)
    int bid = blockIdx.y;
    int mt = 0;
    for (;;) {
        const int c = 12 - ((m0 + mt * 8) >> 5);
        if (bid < c) break;
        bid -= c; ++mt;
    }
    const int ltile = ((m0 + mt * 8) >> 5) + bid;
    const int l0   = ltile * 32;                 // even
    const int bc0  = blockIdx.x * 16;

    const int tid  = threadIdx.x;
    const int wav  = tid >> 6;                   // 0..7 = m offset
    const int lane = tid & 63;
    const int m    = m0 + mt * 8 + wav;
    const int mc   = (m < m_hi) ? m : (m_hi - 1);
    const int par  = mc & 1;                     // (l0 + m) parity base; l0 even
    const int r    = lane & 15;
    const int kg   = (lane >> 4) * 8;

    int lE = l0 + par + 2 * r;     if (lE > LMAX - 1) lE = LMAX - 1;  // rows l = m (mod 2) -> E
    int lO = l0 + 1 - par + 2 * r; if (lO > LMAX - 1) lO = LMAX - 1;  // other parity -> O

    const float* wpE = W + ((size_t)mc * LMAX + lE) * NLAT + kg;
    const float* wpO = W + ((size_t)mc * LMAX + lO) * NLAT + kg;
    const short* eb  = EO + (((size_t)(mc - m0) * 2 + 0) * NJ + bc0 + r) * KFP + kg;
    const short* ob  = EO + (((size_t)(mc - m0) * 2 + 1) * NJ + bc0 + r) * KFP + kg;

    f32x4 accE = {0,0,0,0}, accO = {0,0,0,0};

    f32x4 Ae0, Ae1, Ao0, Ao1, Pe0, Pe1, Po0, Po1;
    bf16x8 Be, Bo, Qe, Qo;

    S2F_LOAD(0, Ae0, Ae1, Ao0, Ao1, Be, Bo);
    #pragma unroll
    for (int t = 0; t < 6; ++t) {
        const int kn = (t + 1) * 32;
        if ((t & 1) == 0) {
            if (t < 5) { S2F_LOAD(kn, Pe0, Pe1, Po0, Po1, Qe, Qo); }
            S2F_COMP(Ae0, Ae1, Ao0, Ao1, Be, Bo);
        } else {
            if (t < 5) { S2F_LOAD(kn, Ae0, Ae1, Ao0, Ao1, Be, Bo); }
            S2F_COMP(Pe0, Pe1, Po0, Po1, Qe, Qo);
        }
    }

    // epilogue: C row R -> l = l0 + par + 2R (E) / l0 + 1 - par + 2R (O)
    const int rowg = (lane >> 4) * 4;
    if (m < m_hi) {
        #pragma unroll
        for (int i = 0; i < 4; ++i) {
            const int R  = rowg + i;
            const int le = l0 + par + 2 * R;
            const int lo = l0 + 1 - par + 2 * R;
            const size_t base = (size_t)(bc0 + r) * LMAX;
            if (le < LMAX) out[(base + le) * MMAX + m] = accE[i];
            if (lo < LMAX) out[(base + lo) * MMAX + m] = accO[i];
        }
    }
}

extern "C" void kernel_launch(void* const* d_in, const int* in_sizes, int n_in,
                              void* d_out, int out_size, void* d_ws, size_t ws_size,
                              hipStream_t stream) {
    const float* x = (const float*)d_in[0];
    const float* w = (const float*)d_in[1];
    float* out = (float*)d_out;

    const size_t XR_OFF = (size_t)FT_ROWS_PAD * FT_COLS * 2;  // 565,248 B
    const size_t PER_M  = (size_t)2 * NJ * KFP * 2;           // 24,576 B per mode
    long cm = 0;
    if (d_ws != nullptr && ws_size > XR_OFF + PER_M) cm = (long)((ws_size - XR_OFF) / PER_M);
    if (cm > MMAX) cm = MMAX;
    if (cm < 1) return;  // ws proven >= 10.05 MB in round 5; unreachable

    short* FT = (short*)d_ws;
    short* EO = (short*)((char*)d_ws + XR_OFF);
    fill_ft_kernel<<<(FT_ROWS_PAD * FT_COLS + 255) / 256, 256, 0, stream>>>(FT);
    for (int m0 = 0; m0 < MMAX; m0 += (int)cm) {
        const int cmx = ((int)cm < MMAX - m0) ? (int)cm : (MMAX - m0);
        stage1_kernel<<<dim3(192), 512, 0, stream>>>(x, FT, EO, m0, cmx);
        const int gym = (cmx + 7) / 8;
        int nblk = 0;
        for (int mtt = 0; mtt < gym; ++mtt) nblk += 12 - ((m0 + mtt * 8) >> 5);
        stage2_kernel<<<dim3(2, nblk), 512, 0, stream>>>(w, EO, out, m0, m0 + cmx);
    }
}

// Round 13
// 71.474 us; speedup vs baseline: 1.2916x; 1.1267x over previous
//
#include <hip/hip_runtime.h>
#include <math.h>

#define NLAT 360
#define NLON 720
#define LMAX 360
#define MMAX 361
#define KPADC 384   // stage-1 cols per bc: 192 kf x 2 (s)
#define KFP  192    // folded-k padded length (180 data + 12 zero pad)
#define FT_COLS 736
#define FT_ROWS_PAD 384
#define NJ   32
#define XST  744

typedef __attribute__((ext_vector_type(4))) float f32x4;
typedef __attribute__((ext_vector_type(8))) short bf16x8;

__device__ __forceinline__ short f2bf(float f) {
    union { float f; unsigned u; } v; v.f = f;
    unsigned r = (v.u + 0x7FFFu + ((v.u >> 16) & 1u)) >> 16;
    return (short)r;
}

// ------- kernel 0: bf16 cosine-DFT matrix FT[m][n], pads written as 0 ------
__global__ __launch_bounds__(256) void fill_ft_kernel(short* __restrict__ FT) {
    int idx = blockIdx.x * 256 + threadIdx.x;
    const int total = FT_ROWS_PAD * FT_COLS;
    if (idx >= total) return;
    int n = idx % FT_COLS;
    int m = idx / FT_COLS;
    short val = 0;
    if (m < MMAX && n < NLON) {
        int t = (m * n) % NLON;
        float s, c;
        sincospif((float)t / 360.0f, &s, &c);
        val = f2bf((6.283185307179586f / 720.0f) * c);
    }
    FT[idx] = val;
}

// ---------------- stage 1: x-panel DFT + parity fold (validated r12) -------
__global__ __launch_bounds__(512) void stage1_kernel(const float* __restrict__ x,
                                                     const short* __restrict__ FT,
                                                     short* __restrict__ EO,
                                                     int m0, int cm) {
    __shared__ __align__(16) short Xs[64][XST];
    const int tid  = threadIdx.x;
    const int wav  = tid >> 6;
    const int lane = tid & 63;
    const int col0 = blockIdx.x * 64;
    const int m_hi = (m0 + cm < MMAX) ? (m0 + cm) : MMAX;

    for (int p = tid; p < 64 * 92; p += 512) {
        const int row = p / 92;
        const int c   = p - row * 92;
        const int gb  = col0 + row;
        const int bc  = gb / KPADC;
        const int q   = gb - bc * KPADC;
        const int kf  = q >> 1;
        const int s   = q & 1;
        const int klat = s ? (NLAT - 1 - kf) : kf;
        f32x4 va = {0,0,0,0}, vb = {0,0,0,0};
        if (c < 90 && kf < 180) {
            const float* xp = x + ((size_t)bc * NLAT + klat) * NLON + c * 8;
            va = *(const f32x4*)xp;
            vb = *(const f32x4*)(xp + 4);
        }
        bf16x8 wv;
        #pragma unroll
        for (int e = 0; e < 4; ++e) { wv[e] = f2bf(va[e]); wv[e + 4] = f2bf(vb[e]); }
        *(bf16x8*)&Xs[row][c * 8] = wv;
    }
    __syncthreads();

    const int r    = lane & 15;
    const int kg   = (lane >> 4) * 8;
    const int rowg = (lane >> 4) * 4;

    for (int mb = m0; mb < m_hi; mb += 256) {
        const int mwb = mb + wav * 32;
        if (mwb >= m_hi) continue;
        int mA0 = mwb + r;      if (mA0 > FT_ROWS_PAD - 1) mA0 = FT_ROWS_PAD - 1;
        int mA1 = mwb + 16 + r; if (mA1 > FT_ROWS_PAD - 1) mA1 = FT_ROWS_PAD - 1;
        const short* ap0 = FT + (size_t)mA0 * FT_COLS + kg;
        const short* ap1 = FT + (size_t)mA1 * FT_COLS + kg;

        f32x4 acc0[4] = {{0,0,0,0},{0,0,0,0},{0,0,0,0},{0,0,0,0}};
        f32x4 acc1[4] = {{0,0,0,0},{0,0,0,0},{0,0,0,0},{0,0,0,0}};

        bf16x8 A0c = *(const bf16x8*)ap0;
        bf16x8 A1c = *(const bf16x8*)ap1;
        #pragma unroll
        for (int t = 0; t < 23; ++t) {
            bf16x8 A0n, A1n;
            if (t < 22) {
                A0n = *(const bf16x8*)(ap0 + (t + 1) * 32);
                A1n = *(const bf16x8*)(ap1 + (t + 1) * 32);
            }
            #pragma unroll
            for (int f = 0; f < 4; ++f) {
                bf16x8 bfr = *(const bf16x8*)&Xs[f * 16 + r][t * 32 + kg];
                acc0[f] = __builtin_amdgcn_mfma_f32_16x16x32_bf16(A0c, bfr, acc0[f], 0, 0, 0);
                acc1[f] = __builtin_amdgcn_mfma_f32_16x16x32_bf16(A1c, bfr, acc1[f], 0, 0, 0);
            }
            A0c = A0n; A1c = A1n;
        }

        #pragma unroll
        for (int f = 0; f < 4; ++f) {
            const int col = col0 + f * 16 + r;
            const int bc  = col / KPADC;
            const int q   = col - bc * KPADC;
            const int kf  = q >> 1;
            const int e   = q & 1;
            #pragma unroll
            for (int i = 0; i < 4; ++i) {
                const int ma = mwb + rowg + i;
                const int mc = ma + 16;
                float v0 = acc0[f][i];
                float p0 = __shfl_xor(v0, 1);
                float val0 = e ? (p0 - v0) : (v0 + p0);
                float v1 = acc1[f][i];
                float p1 = __shfl_xor(v1, 1);
                float val1 = e ? (p1 - v1) : (v1 + p1);
                if (ma < m_hi)
                    EO[(((size_t)(ma - m0) * 2 + e) * NJ + bc) * KFP + kf] = f2bf(val0);
                if (mc < m_hi)
                    EO[(((size_t)(mc - m0) * 2 + e) * NJ + bc) * KFP + kf] = f2bf(val1);
            }
        }
    }
}

// ---------------- stage 2: LDS-staged W (coalesced), parity fold -----------
// Block 256 thr = 4 waves = 4 m; tile 32l x 32bc x 4m, K = 6 steps of 32.
// W staged to LDS parity-split [m][par][17][40] bf16; B = EO direct global.
// T14: next-step global loads issued before barrier, written next iter.
#define S2_GW(T, Wa, Wb, Wc, Wd)                                                \
  { Wa = *(const f32x4*)(wsp0 + (T) * 32);                                      \
    Wb = *(const f32x4*)(wsp0 + (T) * 32 + 4);                                  \
    Wc = *(const f32x4*)(wsp1 + (T) * 32);                                      \
    Wd = *(const f32x4*)(wsp1 + (T) * 32 + 4); }

#define S2_GB(T, B0, B1, B2, B3)                                                \
  { B0 = *(const bf16x8*)(be0 + (T) * 32);                                      \
    B1 = *(const bf16x8*)(be1 + (T) * 32);                                      \
    B2 = *(const bf16x8*)(bo0 + (T) * 32);                                      \
    B3 = *(const bf16x8*)(bo1 + (T) * 32); }

#define S2_WRT(Wa, Wb, Wc, Wd)                                                  \
  { bf16x8 h0, h1;                                                              \
    _Pragma("unroll")                                                           \
    for (int e = 0; e < 4; ++e) {                                               \
      h0[e] = f2bf(Wa[e]); h0[e + 4] = f2bf(Wb[e]);                             \
      h1[e] = f2bf(Wc[e]); h1[e + 4] = f2bf(Wd[e]);                             \
    }                                                                           \
    *(bf16x8*)&Wl[ldso0] = h0;                                                  \
    *(bf16x8*)&Wl[ldso1] = h1; }

#define S2_CMP(B0, B1, B2, B3)                                                  \
  { bf16x8 aEf = *(const bf16x8*)&Wl[aEo];                                      \
    bf16x8 aOf = *(const bf16x8*)&Wl[aOo];                                      \
    accE0 = __builtin_amdgcn_mfma_f32_16x16x32_bf16(aEf, B0, accE0, 0, 0, 0);   \
    accE1 = __builtin_amdgcn_mfma_f32_16x16x32_bf16(aEf, B1, accE1, 0, 0, 0);   \
    accO0 = __builtin_amdgcn_mfma_f32_16x16x32_bf16(aOf, B2, accO0, 0, 0, 0);   \
    accO1 = __builtin_amdgcn_mfma_f32_16x16x32_bf16(aOf, B3, accO1, 0, 0, 0); }

__global__ __launch_bounds__(256) void stage2_kernel(const float* __restrict__ W,
                                                     const short* __restrict__ EO,
                                                     float* __restrict__ out,
                                                     int m0, int m_hi) {
    __shared__ __align__(16) short Wl[4 * 2 * 17 * 40];   // 10,880 B

    // compacted grid decode: blocks per 4-m tile = 12 - ((m0 + mt*4) >> 5)
    int bid = blockIdx.x;
    int mt = 0;
    for (;;) {
        const int c = 12 - ((m0 + mt * 4) >> 5);
        if (bid < c) break;
        bid -= c; ++mt;
    }
    const int ltile = ((m0 + mt * 4) >> 5) + bid;
    const int l0 = ltile * 32;                  // even
    const int mb = m0 + mt * 4;

    const int tid  = threadIdx.x;
    const int wav  = tid >> 6;                  // 0..3 = m offset
    const int lane = tid & 63;
    const int r    = lane & 15;
    const int kg   = (lane >> 4) * 8;

    const int m    = mb + wav;
    const int mc   = (m < m_hi) ? m : (m_hi - 1);
    const int par  = mc & 1;
    const int mloc = mc - m0;

    // staging: 128 rows (4m x 32l) x 32k per step; 4 threads/row, 8 floats each
    const int srr = tid >> 2;                   // 0..63
    const int sq  = (tid & 3) * 8;              // k offset (floats)
    const int moff0 = srr >> 5,        loff0 = srr & 31;
    const int moff1 = (64 + srr) >> 5, loff1 = (64 + srr) & 31;
    int mst0 = mb + moff0; if (mst0 > MMAX - 1) mst0 = MMAX - 1;
    int mst1 = mb + moff1; if (mst1 > MMAX - 1) mst1 = MMAX - 1;
    int lst0 = l0 + loff0; if (lst0 > LMAX - 1) lst0 = LMAX - 1;
    int lst1 = l0 + loff1; if (lst1 > LMAX - 1) lst1 = LMAX - 1;
    const float* wsp0 = W + ((size_t)mst0 * LMAX + lst0) * NLAT + sq;
    const float* wsp1 = W + ((size_t)mst1 * LMAX + lst1) * NLAT + sq;
    const int ldso0 = ((moff0 * 2 + (loff0 & 1)) * 17 + (loff0 >> 1)) * 40 + sq;
    const int ldso1 = ((moff1 * 2 + (loff1 & 1)) * 17 + (loff1 >> 1)) * 40 + sq;

    // B pointers (EO, per-lane; L2-resident)
    const short* be0 = EO + (((size_t)mloc * 2 + 0) * NJ + r)      * KFP + kg;
    const short* be1 = EO + (((size_t)mloc * 2 + 0) * NJ + 16 + r) * KFP + kg;
    const short* bo0 = EO + (((size_t)mloc * 2 + 1) * NJ + r)      * KFP + kg;
    const short* bo1 = EO + (((size_t)mloc * 2 + 1) * NJ + 16 + r) * KFP + kg;

    // A fragment LDS offsets
    const int aEo = ((wav * 2 + par) * 17 + r) * 40 + kg;
    const int aOo = ((wav * 2 + (1 - par)) * 17 + r) * 40 + kg;

    f32x4 accE0 = {0,0,0,0}, accE1 = {0,0,0,0}, accO0 = {0,0,0,0}, accO1 = {0,0,0,0};

    f32x4 wA0, wA1, wA2, wA3, wB0, wB1, wB2, wB3;
    bf16x8 bA0, bA1, bA2, bA3, bB0, bB1, bB2, bB3;

    S2_GW(0, wA0, wA1, wA2, wA3);
    S2_GB(0, bA0, bA1, bA2, bA3);
    #pragma unroll
    for (int t = 0; t < 6; ++t) {
        if ((t & 1) == 0) {
            S2_WRT(wA0, wA1, wA2, wA3);
            if (t < 5) { S2_GW(t + 1, wB0, wB1, wB2, wB3); S2_GB(t + 1, bB0, bB1, bB2, bB3); }
            __syncthreads();
            S2_CMP(bA0, bA1, bA2, bA3);
            __syncthreads();
        } else {
            S2_WRT(wB0, wB1, wB2, wB3);
            if (t < 5) { S2_GW(t + 1, wA0, wA1, wA2, wA3); S2_GB(t + 1, bA0, bA1, bA2, bA3); }
            __syncthreads();
            S2_CMP(bB0, bB1, bB2, bB3);
            __syncthreads();
        }
    }

    // epilogue: row R -> l = l0 + par + 2R (E) / l0 + 1 - par + 2R (O);
    // cols: accE0/accO0 -> bc = r, accE1/accO1 -> bc = 16 + r
    const int rowg = (lane >> 4) * 4;
    if (m < m_hi) {
        #pragma unroll
        for (int i = 0; i < 4; ++i) {
            const int R  = rowg + i;
            const int le = l0 + par + 2 * R;
            const int lo = l0 + 1 - par + 2 * R;
            const size_t b0 = (size_t)r * LMAX;
            const size_t b1 = (size_t)(16 + r) * LMAX;
            if (le < LMAX) {
                out[(b0 + le) * MMAX + m] = accE0[i];
                out[(b1 + le) * MMAX + m] = accE1[i];
            }
            if (lo < LMAX) {
                out[(b0 + lo) * MMAX + m] = accO0[i];
                out[(b1 + lo) * MMAX + m] = accO1[i];
            }
        }
    }
}

extern "C" void kernel_launch(void* const* d_in, const int* in_sizes, int n_in,
                              void* d_out, int out_size, void* d_ws, size_t ws_size,
                              hipStream_t stream) {
    const float* x = (const float*)d_in[0];
    const float* w = (const float*)d_in[1];
    float* out = (float*)d_out;

    const size_t XR_OFF = (size_t)FT_ROWS_PAD * FT_COLS * 2;  // 565,248 B
    const size_t PER_M  = (size_t)2 * NJ * KFP * 2;           // 24,576 B per mode
    long cm = 0;
    if (d_ws != nullptr && ws_size > XR_OFF + PER_M) cm = (long)((ws_size - XR_OFF) / PER_M);
    if (cm > MMAX) cm = MMAX;
    if (cm < 1) return;

    short* FT = (short*)d_ws;
    short* EO = (short*)((char*)d_ws + XR_OFF);
    fill_ft_kernel<<<(FT_ROWS_PAD * FT_COLS + 255) / 256, 256, 0, stream>>>(FT);
    for (int m0 = 0; m0 < MMAX; m0 += (int)cm) {
        const int cmx = ((int)cm < MMAX - m0) ? (int)cm : (MMAX - m0);
        stage1_kernel<<<dim3(192), 512, 0, stream>>>(x, FT, EO, m0, cmx);
        const int gym = (cmx + 3) / 4;
        int nblk = 0;
        for (int mtt = 0; mtt < gym; ++mtt) nblk += 12 - ((m0 + mtt * 4) >> 5);
        stage2_kernel<<<dim3(nblk), 256, 0, stream>>>(w, EO, out, m0, m0 + cmx);
    }
}